// Round 18
// baseline (167.652 us; speedup 1.0000x reference)
//
#include <hip/hip_runtime.h>
#include <hip/hip_bf16.h>

// InfoNCE loss, N=4096, D=1024, TEMP=0.07.
// loss = mean_i( -pos_i + lse_i ), lse over sim rows with diagonal masked.
// Fixed-max LSE (rows unit-norm -> sim <= 1/T): partials are order-independent.
// Symmetry via 128x128 tiles, upper triangle (J >= I).
//
// R18: BARRIER-FREE K-loop. Each of the 4 waves owns a private 64x64 output
// tile and a private ring-2 LDS buffer (2 x 8 KB = A[64][32]+B[64][32] per
// slot), staged by its own 8 global_load_lds per step. No s_barrier in the
// loop: per-wave counted vmcnt(8) gates slot readiness; one lgkmcnt(0)
// orders frag reads before the overwrite-stage. 8 independent wave
// pipelines per CU (2 blocks x 4 waves, 64 KiB LDS/block). Trade: 2x staging
// (A/B duplicated across the wave pair) -- zb is L2-resident, cheap.
// Same verified zero-conflict XOR swizzle, 16x16x32 MFMA, plane-store
// epilogue, Ji-bounded reduce (all from R13, absmax 0.0).

typedef __attribute__((ext_vector_type(8))) short bf16x8;
typedef __attribute__((ext_vector_type(4))) float f32x4;

#define NN 4096
#define TWO_N 8192
#define DIM 1024
#define TEMP_INV 14.285714285714286f
#define EXP_SCALE 20.609929155566303f /* log2(e)/0.07 */
#define NT 64     /* tiles of 128 per dim */
#define NBLK 2080 /* 64*65/2 upper-tri tiles; 2080 % 8 == 0 -> bijective */
#define WSLOT 4096 /* shorts per wave-slot: A[64][32] + B[64][32] = 8 KB */

#define GLD16(g, l)                                                          \
  __builtin_amdgcn_global_load_lds(                                          \
      (const __attribute__((address_space(1))) void*)(g),                    \
      (__attribute__((address_space(3))) void*)(l), 16, 0, 0)

__device__ __forceinline__ unsigned short f2bf(float f) {
  unsigned int u = __float_as_uint(f);
  u += 0x7fffu + ((u >> 16) & 1u);  // RNE
  return (unsigned short)(u >> 16);
}

// Fused: fp32->bf16 cast of z=[z1;z2] AND pos[row]=dot(z1,z2)/T (one 32MB read).
__global__ __launch_bounds__(256) void prep_kernel(
    const float* __restrict__ z1, const float* __restrict__ z2,
    unsigned short* __restrict__ zb, float* __restrict__ pos) {
  const int row = blockIdx.x, t = threadIdx.x;
  float4 a = ((const float4*)(z1 + (size_t)row * DIM))[t];
  float4 b = ((const float4*)(z2 + (size_t)row * DIM))[t];
  ushort4 ua = {f2bf(a.x), f2bf(a.y), f2bf(a.z), f2bf(a.w)};
  ushort4 ub = {f2bf(b.x), f2bf(b.y), f2bf(b.z), f2bf(b.w)};
  ((ushort4*)(zb + (size_t)row * DIM))[t] = ua;
  ((ushort4*)(zb + (size_t)(NN + row) * DIM))[t] = ub;
  float s = a.x * b.x + a.y * b.y + a.z * b.z + a.w * b.w;
#pragma unroll
  for (int off = 1; off < 64; off <<= 1) s += __shfl_xor(s, off);
  __shared__ float tmp[4];
  if ((t & 63) == 0) tmp[t >> 6] = s;
  __syncthreads();
  if (t == 0) pos[row] = (tmp[0] + tmp[1] + tmp[2] + tmp[3]) * TEMP_INV;
}

__global__ __launch_bounds__(256, 2) void lse_kernel(
    const unsigned short* __restrict__ zb, float* __restrict__ part) {
  __shared__ unsigned short lds[4 * 2 * WSLOT];  // 64 KiB: [wave][slot][4096]
  // ---- tile decode: XCD swizzle -> upper-tri (I, J), J >= I ----
  int u = ((int)blockIdx.x & 7) * (NBLK / 8) + ((int)blockIdx.x >> 3);
  int I = 0, rem = u;
  while (rem >= NT - I) { rem -= NT - I; ++I; }
  const int J = I + rem;
  const int rowA0 = I * 128, colB0 = J * 128;
  const bool diag = (I == J);

  const int t = threadIdx.x;
  const int wave = t >> 6, lane = t & 63;
  const int wm = wave >> 1, wn = wave & 1;  // 2x2 waves, each 64x64 out
  const int lo = lane & 15, hi = lane >> 4;

  unsigned short* wbase = lds + wave * (2 * WSLOT);  // private 16 KB

  // ---- wave-private staging: 4 A-chunks + 4 B-chunks (16B) per lane/slot.
  // Chunk c = i*64+lane (c in 0..255): local row r=c>>2, phys group p=c&3
  // holds logical lg = p ^ ((r>>1)&3) (inverse of read-side XOR).
  const unsigned short* gA = zb + (size_t)(rowA0 + wm * 64) * DIM;
  const unsigned short* gB = zb + (size_t)(colB0 + wn * 64) * DIM;
  int oAB[4];
#pragma unroll
  for (int i = 0; i < 4; ++i) {
    int c = i * 64 + lane, r = c >> 2, p = c & 3;
    oAB[i] = r * DIM + (p ^ ((r >> 1) & 3)) * 8;  // same for A and B strips
  }

  // ---- read-side swizzled offsets (shorts), local rows 0..63 ----
  const int sx = (hi ^ ((lo >> 1) & 3)) * 8;  // swizzled 16B group

  f32x4 acc[4][4];
#pragma unroll
  for (int m = 0; m < 4; ++m)
#pragma unroll
    for (int n = 0; n < 4; ++n) acc[m][n] = (f32x4){0.f, 0.f, 0.f, 0.f};

  // Stage K-step k into wave-private slot sl (8 gld16: 4 A + 4 B).
#define STAGE(sl_, k_)                                                        \
  {                                                                           \
    const unsigned short* ga = gA + ((k_) & 31) * 32;                         \
    const unsigned short* gb = gB + ((k_) & 31) * 32;                         \
    unsigned short* d = wbase + (sl_) * WSLOT;                                \
    GLD16(ga + oAB[0], d);                                                    \
    GLD16(ga + oAB[1], d + 512);                                              \
    GLD16(ga + oAB[2], d + 1024);                                             \
    GLD16(ga + oAB[3], d + 1536);                                             \
    GLD16(gb + oAB[0], d + 2048);                                             \
    GLD16(gb + oAB[1], d + 2560);                                             \
    GLD16(gb + oAB[2], d + 3072);                                             \
    GLD16(gb + oAB[3], d + 3584);                                             \
  }

  STAGE(0, 0);
  STAGE(1, 1);

#pragma unroll 1
  for (int s = 0; s < DIM / 32; ++s) {
    // Gate: 8 newest (slot s+1, issued last iter) stay in flight; the 8
    // older (slot s) must be landed. Wave-private -> no barrier needed.
    asm volatile("s_waitcnt vmcnt(8)" ::: "memory");
    const unsigned short* slot = wbase + (s & 1) * WSLOT;
    bf16x8 af[4], bg[4];
#pragma unroll
    for (int m = 0; m < 4; ++m)
      af[m] = *(const bf16x8*)(slot + (m * 16 + lo) * 32 + sx);
#pragma unroll
    for (int n = 0; n < 4; ++n)
      bg[n] = *(const bf16x8*)(slot + 2048 + (n * 16 + lo) * 32 + sx);
    // Drain own frag reads before overwriting this slot with tile s+2.
    asm volatile("s_waitcnt lgkmcnt(0)" ::: "memory");
    STAGE(s & 1, s + 2);  // s>=30: dummy wrap (k&31), never read
    __builtin_amdgcn_s_setprio(1);
#pragma unroll
    for (int m = 0; m < 4; ++m)
#pragma unroll
      for (int n = 0; n < 4; ++n)
        acc[m][n] = __builtin_amdgcn_mfma_f32_16x16x32_bf16(af[m], bg[n], acc[m][n], 0, 0, 0);
    __builtin_amdgcn_s_setprio(0);
  }
  asm volatile("s_waitcnt vmcnt(0) lgkmcnt(0)" ::: "memory");  // drain dummies

  // ---- epilogue: e=exp((dot-1)/T), diag masked; row/col partial sums ----
  // NO atomics: plane stores (row partials keyed (J,wn) -> planes 0..127;
  // col partials keyed (I,wm) -> planes 128..255). Waves sharing a plane
  // write disjoint rows/cols (wm/wn offsets).
  float* rplane = part + (size_t)(2 * J + wn) * TWO_N;
  float* cplane = part + (size_t)(128 + 2 * I + wm) * TWO_N;
  float csum[4] = {0.f, 0.f, 0.f, 0.f};
#pragma unroll
  for (int m = 0; m < 4; ++m) {
#pragma unroll
    for (int r = 0; r < 4; ++r) {
      const int grow = rowA0 + wm * 64 + m * 16 + hi * 4 + r;  // row=(lane>>4)*4+reg
      float s = 0.f;
#pragma unroll
      for (int n = 0; n < 4; ++n) {
        const int gcol = colB0 + wn * 64 + n * 16 + lo;        // col=lane&15
        float e = exp2f((acc[m][n][r] - 1.0f) * EXP_SCALE);
        if (grow == gcol) e = 0.f;  // mask self-similarity (diag tiles)
        s += e;
        csum[n] += e;
      }
      s += __shfl_xor(s, 1); s += __shfl_xor(s, 2);
      s += __shfl_xor(s, 4); s += __shfl_xor(s, 8);
      if (lo == 0) rplane[grow] = s;  // 4 lanes, 64 distinct rows per wave
    }
  }
  if (!diag) {  // off-diagonal tiles feed transposed rows via col sums
#pragma unroll
    for (int n = 0; n < 4; ++n) {
      float s = csum[n];
      s += __shfl_xor(s, 16); s += __shfl_xor(s, 32);
      if (hi == 0) cplane[colB0 + wn * 64 + n * 16 + lo] = s;  // 16 lanes
    }
  }
#undef STAGE
}

// Fold only the provably-written plane entries -> per-row term -> mean.
// For row i (Ji = i>>7): row-planes 2J+{0,1} are written iff J >= Ji;
// col-planes 128+2I+{0,1} iff I < Ji. Exactly 128 entries per row, so no
// workspace memset is needed (stale bytes are never read).
__global__ __launch_bounds__(256) void reduce_finalize_kernel(
    const float* __restrict__ part, const float* __restrict__ pos,
    float* __restrict__ out) {
  const int i = blockIdx.x * 256 + threadIdx.x;
  const int Ji = i >> 7;
  float s = 0.f;
  for (int J = Ji; J < NT; ++J)
    s += part[(size_t)(2 * J) * TWO_N + i] + part[(size_t)(2 * J + 1) * TWO_N + i];
  for (int I = 0; I < Ji; ++I)
    s += part[(size_t)(128 + 2 * I) * TWO_N + i] +
         part[(size_t)(128 + 2 * I + 1) * TWO_N + i];
  float term = TEMP_INV + logf(s) - pos[i & (NN - 1)];
#pragma unroll
  for (int off = 1; off < 64; off <<= 1) term += __shfl_xor(term, off);
  __shared__ float tmp[4];
  const int t = threadIdx.x;
  if ((t & 63) == 0) tmp[t >> 6] = term;
  __syncthreads();
  if (t == 0)
    atomicAdd(out, (tmp[0] + tmp[1] + tmp[2] + tmp[3]) * (1.0f / (float)TWO_N));
}

extern "C" void kernel_launch(void* const* d_in, const int* in_sizes, int n_in,
                              void* d_out, int out_size, void* d_ws, size_t ws_size,
                              hipStream_t stream) {
  const float* z1 = (const float*)d_in[0];
  const float* z2 = (const float*)d_in[1];
  float* out = (float*)d_out;

  char* ws = (char*)d_ws;
  unsigned short* zb = (unsigned short*)ws;            // 16 MB bf16 z
  size_t off = (size_t)TWO_N * DIM * 2;
  float* part = (float*)(ws + off);                    // 8 MB: 256 x 8192 f32
  off += (size_t)256 * TWO_N * 4;
  float* pos = (float*)(ws + off);                     // 16 KB

  hipMemsetAsync(out, 0, sizeof(float), stream);
  prep_kernel<<<NN, 256, 0, stream>>>(z1, z2, zb, pos);
  lse_kernel<<<NBLK, 256, 0, stream>>>(zb, part);
  reduce_finalize_kernel<<<TWO_N / 256, 256, 0, stream>>>(part, pos, out);
}

// Round 19
// 96.274 us; speedup vs baseline: 1.7414x; 1.7414x over previous
//
#include <hip/hip_runtime.h>
#include <hip/hip_bf16.h>

// InfoNCE loss, N=4096, D=1024, TEMP=0.07.
// loss = mean_i( -pos_i + lse_i ), lse over sim rows with diagonal masked.
// Fixed-max LSE (rows unit-norm -> sim <= 1/T): partials are order-independent.
// Symmetry via 128x128 tiles, upper triangle (J >= I).
//
// R19: fp8 x 4-blocks/CU. R13 skeleton (128x128 tile, 4 waves 2x2, ring-2
// dbuf 32 KiB, counted vmcnt(4), 2 barriers/step, plane-store epilogue,
// Ji-bounded reduce) with R6's verified MX-fp8 datapath: BK=64 per step ->
// 16 steps instead of 32 (halves barrier/gate overhead), half LDS bytes,
// mfma_scale_f32_32x32x64_f8f6f4 with unit scales. acc = 2x2 f32x16 = 64
// AGPR (same as R13). Epilogue = R17's verified 32x32 C/D layout.

typedef __attribute__((ext_vector_type(4))) int i32x4;
typedef __attribute__((ext_vector_type(8))) int i32x8;
typedef __attribute__((ext_vector_type(16))) float f32x16;

#define NN 4096
#define TWO_N 8192
#define DIM 1024
#define TEMP_INV 14.285714285714286f
#define EXP_SCALE 20.609929155566303f /* log2(e)/0.07 */
#define NT 64     /* tiles of 128 per dim */
#define NBLK 2080 /* 64*65/2 upper-tri tiles; 2080 % 8 == 0 -> bijective */
#define SLOTB 16384 /* bytes per slot: A[128][64] + B[128][64] */

#define GLD16(g, l)                                                          \
  __builtin_amdgcn_global_load_lds(                                          \
      (const __attribute__((address_space(1))) void*)(g),                    \
      (__attribute__((address_space(3))) void*)(l), 16, 0, 0)

// Fused: fp32->fp8(e4m3) cast of z=[z1;z2] AND pos=dot(z1,z2)/T in fp32.
// (Verified R6: absmax 0.0 at threshold 0.1825.)
__global__ __launch_bounds__(256) void prep_kernel(
    const float* __restrict__ z1, const float* __restrict__ z2,
    unsigned int* __restrict__ zf8, float* __restrict__ pos) {
  const int row = blockIdx.x, t = threadIdx.x;
  float4 a = ((const float4*)(z1 + (size_t)row * DIM))[t];
  float4 b = ((const float4*)(z2 + (size_t)row * DIM))[t];
  int wa = __builtin_amdgcn_cvt_pk_fp8_f32(a.x, a.y, 0, false);
  wa = __builtin_amdgcn_cvt_pk_fp8_f32(a.z, a.w, wa, true);
  int wb = __builtin_amdgcn_cvt_pk_fp8_f32(b.x, b.y, 0, false);
  wb = __builtin_amdgcn_cvt_pk_fp8_f32(b.z, b.w, wb, true);
  zf8[(size_t)row * (DIM / 4) + t] = (unsigned int)wa;
  zf8[(size_t)(NN + row) * (DIM / 4) + t] = (unsigned int)wb;
  float s = a.x * b.x + a.y * b.y + a.z * b.z + a.w * b.w;
#pragma unroll
  for (int off = 1; off < 64; off <<= 1) s += __shfl_xor(s, off);
  __shared__ float tmp[4];
  if ((t & 63) == 0) tmp[t >> 6] = s;
  __syncthreads();
  if (t == 0) pos[row] = (tmp[0] + tmp[1] + tmp[2] + tmp[3]) * TEMP_INV;
}

__global__ __launch_bounds__(256, 4) void lse_kernel(
    const unsigned char* __restrict__ zb8, float* __restrict__ part) {
  __shared__ unsigned char lds[2 * SLOTB];  // 32 KiB; 4 blocks/CU = 128 KiB
  // ---- tile decode: XCD swizzle -> upper-tri (I, J), J >= I ----
  int u = ((int)blockIdx.x & 7) * (NBLK / 8) + ((int)blockIdx.x >> 3);
  int I = 0, rem = u;
  while (rem >= NT - I) { rem -= NT - I; ++I; }
  const int J = I + rem;
  const int rowA0 = I * 128, colB0 = J * 128;
  const bool diag = (I == J);

  const int t = threadIdx.x;
  const int wave = t >> 6, lane = t & 63;
  const int wm = wave >> 1, wn = wave & 1;  // 2x2 waves, each 64x64 out
  const int l31 = lane & 31, kh = lane >> 5;

  // ---- staging: 2 A-chunks + 2 B-chunks (16B each) per thread per slot ----
  // slot layout (bytes): A[128 rows][64] at 0, B[128][64] at 8192. Chunk c
  // (16B): row=c>>2, phys group p=c&3 holds logical lg = p ^ ((row>>1)&3)
  // (inverse of the read-side XOR). LDS dest linear (wave-uniform + lane*16).
  int oA[2], oB[2];
#pragma unroll
  for (int i = 0; i < 2; ++i) {
    int c = i * 256 + t, row = c >> 2, p = c & 3;
    oA[i] = (rowA0 + row) * DIM + (p ^ ((row >> 1) & 3)) * 16;
    oB[i] = (colB0 + row) * DIM + (p ^ ((row >> 1) & 3)) * 16;
  }

  const int arow_l = wm * 64 + l31;  // + m*32 : local A row for frags
  const int brow_l = wn * 64 + l31;  // + n*32 : local B row

  f32x16 acc[2][2];
#pragma unroll
  for (int m = 0; m < 2; ++m)
#pragma unroll
    for (int n = 0; n < 2; ++n)
#pragma unroll
      for (int r = 0; r < 16; ++r) acc[m][n][r] = 0.f;

#define STAGE(dst_, k_)                                                       \
  {                                                                           \
    const unsigned char* gk = zb8 + ((k_) & 15) * 64;                         \
    GLD16(gk + oA[0], (dst_) + wave * 1024);                                  \
    GLD16(gk + oA[1], (dst_) + 4096 + wave * 1024);                           \
    GLD16(gk + oB[0], (dst_) + 8192 + wave * 1024);                           \
    GLD16(gk + oB[1], (dst_) + 8192 + 4096 + wave * 1024);                    \
  }

  // Read one 32x64 fp8 fragment row-slice: lane reads 32 B of local row
  // rloc at logical 16B-groups {2kh, 2kh+1}, phys = g ^ ((rloc>>1)&3).
#define READ_FRAG(F, base_, rloc_)                                            \
  {                                                                           \
    const unsigned char* rb_ = (base_) + (rloc_) * 64;                        \
    const int cls_ = ((rloc_) >> 1) & 3;                                      \
    i32x4 lo_ = *(const i32x4*)(rb_ + (((2 * kh) ^ cls_) << 4));              \
    i32x4 hi_ = *(const i32x4*)(rb_ + (((2 * kh + 1) ^ cls_) << 4));          \
    F[0] = lo_[0]; F[1] = lo_[1]; F[2] = lo_[2]; F[3] = lo_[3];               \
    F[4] = hi_[0]; F[5] = hi_[1]; F[6] = hi_[2]; F[7] = hi_[3];               \
  }

  unsigned char* cur = lds;          // slot holding tile s
  unsigned char* oth = lds + SLOTB;  // stage target (tile s+1)

  STAGE(cur, 0);
  asm volatile("s_waitcnt vmcnt(0)" ::: "memory");  // own slot-0 loads done

#pragma unroll 1
  for (int s = 0; s < DIM / 64; ++s) {
    __builtin_amdgcn_s_barrier();  // BAR_A: all waves done reading oth (s-1)
    __builtin_amdgcn_sched_barrier(0);
    STAGE(oth, s + 1);             // s=15: dummy wrap (k&15=0), never read
    asm volatile("s_waitcnt vmcnt(4)" ::: "memory");  // own slot-s loads done
    __builtin_amdgcn_s_barrier();  // BAR_B: slot s published across waves
    __builtin_amdgcn_sched_barrier(0);

    i32x8 a0, a1, b0, b1;
    READ_FRAG(a0, cur, arow_l);
    READ_FRAG(a1, cur, arow_l + 32);
    READ_FRAG(b0, cur + 8192, brow_l);
    READ_FRAG(b1, cur + 8192, brow_l + 32);
    __builtin_amdgcn_s_setprio(1);
    acc[0][0] = __builtin_amdgcn_mfma_scale_f32_32x32x64_f8f6f4(
        a0, b0, acc[0][0], 0, 0, 0, 127, 0, 127);
    acc[0][1] = __builtin_amdgcn_mfma_scale_f32_32x32x64_f8f6f4(
        a0, b1, acc[0][1], 0, 0, 0, 127, 0, 127);
    acc[1][0] = __builtin_amdgcn_mfma_scale_f32_32x32x64_f8f6f4(
        a1, b0, acc[1][0], 0, 0, 0, 127, 0, 127);
    acc[1][1] = __builtin_amdgcn_mfma_scale_f32_32x32x64_f8f6f4(
        a1, b1, acc[1][1], 0, 0, 0, 127, 0, 127);
    __builtin_amdgcn_s_setprio(0);
    unsigned char* tmp_ = cur; cur = oth; oth = tmp_;  // swap buffers
  }
  asm volatile("s_waitcnt vmcnt(0) lgkmcnt(0)" ::: "memory");  // drain dummy

  // ---- epilogue: e=exp((dot-1)/T), diag masked; row/col partial sums ----
  // C/D 32x32: col = lane&31, row = (reg&3) + 8*(reg>>2) + 4*(lane>>5)
  // (verified R6/R17). NO atomics: plane stores (row partials keyed (J,wn)
  // -> planes 0..127; col partials keyed (I,wm) -> planes 128..255).
  float* rplane = part + (size_t)(2 * J + wn) * TWO_N;
  float* cplane = part + (size_t)(128 + 2 * I + wm) * TWO_N;
  float csum[2] = {0.f, 0.f};
#pragma unroll
  for (int m = 0; m < 2; ++m) {
#pragma unroll
    for (int r = 0; r < 16; ++r) {
      const int grow = rowA0 + wm * 64 + m * 32 + (r & 3) + 8 * (r >> 2) + 4 * kh;
      float s = 0.f;
#pragma unroll
      for (int n = 0; n < 2; ++n) {
        const int gcol = colB0 + wn * 64 + n * 32 + l31;
        float e = exp2f((acc[m][n][r] - 1.0f) * EXP_SCALE);
        if (grow == gcol) e = 0.f;  // mask self-similarity (diag tiles)
        s += e;
        csum[n] += e;
      }
      s += __shfl_xor(s, 1); s += __shfl_xor(s, 2); s += __shfl_xor(s, 4);
      s += __shfl_xor(s, 8); s += __shfl_xor(s, 16);
      if (l31 == 0) rplane[grow] = s;  // lanes 0,32: distinct rows (kh)
    }
  }
  if (!diag) {  // off-diagonal tiles feed transposed rows via col sums
#pragma unroll
    for (int n = 0; n < 2; ++n) {
      float c = csum[n];
      c += __shfl_xor(c, 32);  // combine kh halves (same col, disjoint rows)
      if (lane < 32) cplane[colB0 + wn * 64 + n * 32 + lane] = c;
    }
  }
#undef READ_FRAG
#undef STAGE
}

// Fold only the provably-written plane entries -> per-row term -> mean.
// For row i (Ji = i>>7): row-planes 2J+{0,1} are written iff J >= Ji;
// col-planes 128+2I+{0,1} iff I < Ji. Exactly 128 entries per row, so no
// workspace memset is needed (stale bytes are never read).
__global__ __launch_bounds__(256) void reduce_finalize_kernel(
    const float* __restrict__ part, const float* __restrict__ pos,
    float* __restrict__ out) {
  const int i = blockIdx.x * 256 + threadIdx.x;
  const int Ji = i >> 7;
  float s = 0.f;
  for (int J = Ji; J < NT; ++J)
    s += part[(size_t)(2 * J) * TWO_N + i] + part[(size_t)(2 * J + 1) * TWO_N + i];
  for (int I = 0; I < Ji; ++I)
    s += part[(size_t)(128 + 2 * I) * TWO_N + i] +
         part[(size_t)(128 + 2 * I + 1) * TWO_N + i];
  float term = TEMP_INV + logf(s) - pos[i & (NN - 1)];
#pragma unroll
  for (int off = 1; off < 64; off <<= 1) term += __shfl_xor(term, off);
  __shared__ float tmp[4];
  const int t = threadIdx.x;
  if ((t & 63) == 0) tmp[t >> 6] = term;
  __syncthreads();
  if (t == 0)
    atomicAdd(out, (tmp[0] + tmp[1] + tmp[2] + tmp[3]) * (1.0f / (float)TWO_N));
}

extern "C" void kernel_launch(void* const* d_in, const int* in_sizes, int n_in,
                              void* d_out, int out_size, void* d_ws, size_t ws_size,
                              hipStream_t stream) {
  const float* z1 = (const float*)d_in[0];
  const float* z2 = (const float*)d_in[1];
  float* out = (float*)d_out;

  char* ws = (char*)d_ws;
  unsigned char* zf8 = (unsigned char*)ws;             // 8 MB fp8 z
  size_t off = (size_t)TWO_N * DIM;
  float* part = (float*)(ws + off);                    // 8 MB: 256 x 8192 f32
  off += (size_t)256 * TWO_N * 4;
  float* pos = (float*)(ws + off);                     // 16 KB

  hipMemsetAsync(out, 0, sizeof(float), stream);
  prep_kernel<<<NN, 256, 0, stream>>>(z1, z2, (unsigned int*)zf8, pos);
  lse_kernel<<<NBLK, 256, 0, stream>>>(zf8, part);
  reduce_finalize_kernel<<<TWO_N / 256, 256, 0, stream>>>(part, pos, out);
}